// Round 1
// baseline (109.065 us; speedup 1.0000x reference)
//
#include <hip/hip_runtime.h>

#define GLOBAL_AS __attribute__((address_space(1)))
#define LDS_AS __attribute__((address_space(3)))

// Problem constants (fixed by reference setup_inputs)
constexpr int Bc = 8;
constexpr int Sc = 4096;
constexpr int Dc = 2048;
constexpr int Ec = 16;
constexpr int NTOK = Bc * Sc;            // 32768 tokens
constexpr int TOK_PER_BLK = 64;
constexpr int NBLK = NTOK / TOK_PER_BLK; // 512 blocks (2 per CU)
constexpr float EPS = 1e-6f;
constexpr float CAPACITY = 8.0f;         // int(1.0 * B)

// ---------------------------------------------------------------------------
// Stage one 2048-float token row (8 KB) into LDS: 8 x global_load_lds dwordx4
// per lane. LDS dest is linear in lane order (base + lane*16B) as HW requires.
// ---------------------------------------------------------------------------
__device__ __forceinline__ void stage_row16(const float* src, float* dst, int lane) {
#pragma unroll
  for (int r = 0; r < 8; ++r) {
    __builtin_amdgcn_global_load_lds(
        (const GLOBAL_AS void*)(src + r * 256 + lane * 4),
        (LDS_AS void*)(dst + r * 256 + lane * 4),
        16, 0, 0);
  }
}

// ---------------------------------------------------------------------------
// K1: logits[token][e] = dot(X[token], W[e]).  (bias added in K2)
// 4 waves/block; wave w owns experts 4w..4w+3, W held in 128 VGPRs/lane.
// Each wave privately double-buffers token rows in LDS -> no __syncthreads,
// manual vmcnt pipelining.
// ---------------------------------------------------------------------------
__global__ __launch_bounds__(256, 2) void k1_logits(
    const float* __restrict__ X, const float* __restrict__ W,
    float* __restrict__ logits) {
  __shared__ __align__(16) float xbuf[4][2][Dc];  // 64 KB

  const int tid  = threadIdx.x;
  const int w    = tid >> 6;    // wave id 0..3 (uniform within wave)
  const int lane = tid & 63;
  const int e0   = w * 4;

  // W fragments: wreg[e_loc][i] covers d = i*256 + lane*4 + {0..3}
  float4 wreg[4][8];
#pragma unroll
  for (int e = 0; e < 4; ++e) {
#pragma unroll
    for (int i = 0; i < 8; ++i) {
      wreg[e][i] = *reinterpret_cast<const float4*>(
          W + (size_t)(e0 + e) * Dc + i * 256 + lane * 4);
    }
  }

  const int tok0 = blockIdx.x * TOK_PER_BLK;

  // prologue: stage token 0 into buffer 0
  stage_row16(X + (size_t)tok0 * Dc, &xbuf[w][0][0], lane);

  for (int t = 0; t < TOK_PER_BLK; ++t) {
    const int buf = t & 1;
    if (t < TOK_PER_BLK - 1) {
      stage_row16(X + (size_t)(tok0 + t + 1) * Dc, &xbuf[w][buf ^ 1][0], lane);
      // wait for current buffer (everything except the 8 loads just issued)
      asm volatile("s_waitcnt vmcnt(8)" ::: "memory");
    } else {
      asm volatile("s_waitcnt vmcnt(0)" ::: "memory");
    }

    const float* xb = &xbuf[w][buf][0];
    float a0 = 0.f, a1 = 0.f, a2 = 0.f, a3 = 0.f;
#pragma unroll
    for (int i = 0; i < 8; ++i) {
      const float4 xv = *reinterpret_cast<const float4*>(xb + i * 256 + lane * 4);
      a0 = fmaf(xv.x, wreg[0][i].x, a0);
      a0 = fmaf(xv.y, wreg[0][i].y, a0);
      a0 = fmaf(xv.z, wreg[0][i].z, a0);
      a0 = fmaf(xv.w, wreg[0][i].w, a0);
      a1 = fmaf(xv.x, wreg[1][i].x, a1);
      a1 = fmaf(xv.y, wreg[1][i].y, a1);
      a1 = fmaf(xv.z, wreg[1][i].z, a1);
      a1 = fmaf(xv.w, wreg[1][i].w, a1);
      a2 = fmaf(xv.x, wreg[2][i].x, a2);
      a2 = fmaf(xv.y, wreg[2][i].y, a2);
      a2 = fmaf(xv.z, wreg[2][i].z, a2);
      a2 = fmaf(xv.w, wreg[2][i].w, a2);
      a3 = fmaf(xv.x, wreg[3][i].x, a3);
      a3 = fmaf(xv.y, wreg[3][i].y, a3);
      a3 = fmaf(xv.z, wreg[3][i].z, a3);
      a3 = fmaf(xv.w, wreg[3][i].w, a3);
    }

    // tree-reduce each expert partial across the 64 lanes
#pragma unroll
    for (int m = 32; m >= 1; m >>= 1) {
      a0 += __shfl_xor(a0, m, 64);
      a1 += __shfl_xor(a1, m, 64);
      a2 += __shfl_xor(a2, m, 64);
      a3 += __shfl_xor(a3, m, 64);
    }

    if (lane == 0) {
      float4 r;
      r.x = a0; r.y = a1; r.z = a2; r.w = a3;
      *reinterpret_cast<float4*>(logits + (size_t)(tok0 + t) * Ec + e0) = r;
    }
  }
}

// ---------------------------------------------------------------------------
// K2: per token, in place on buf (= d_out):
//   l = logits + bias; gate = softmax(l); mask = top-8 of l (ties -> lower
//   index, matching jax.lax.top_k); buf <- gate * mask
// ---------------------------------------------------------------------------
__global__ __launch_bounds__(256) void k2_gate(float* __restrict__ buf,
                                               const float* __restrict__ bias) {
  const int t = blockIdx.x * 256 + threadIdx.x;
  if (t >= NTOK) return;

  float4* p = reinterpret_cast<float4*>(buf + (size_t)t * Ec);
  float l[16];
#pragma unroll
  for (int q = 0; q < 4; ++q) {
    const float4 v = p[q];
    l[q * 4 + 0] = v.x;
    l[q * 4 + 1] = v.y;
    l[q * 4 + 2] = v.z;
    l[q * 4 + 3] = v.w;
  }
#pragma unroll
  for (int i = 0; i < 16; ++i) l[i] += bias[i];

  float m = l[0];
#pragma unroll
  for (int i = 1; i < 16; ++i) m = fmaxf(m, l[i]);

  float ex[16];
  float Z = 0.f;
#pragma unroll
  for (int i = 0; i < 16; ++i) {
    ex[i] = expf(l[i] - m);
    Z += ex[i];
  }
  const float invZ = 1.0f / Z;

  float g[16];
#pragma unroll
  for (int i = 0; i < 16; ++i) {
    int cnt = 0;
#pragma unroll
    for (int j = 0; j < 16; ++j) {
      cnt += (l[j] > l[i]) || ((l[j] == l[i]) && (j < i));
    }
    g[i] = (cnt < 8) ? ex[i] * invZ : 0.0f;
  }

#pragma unroll
  for (int q = 0; q < 4; ++q) {
    float4 v;
    v.x = g[q * 4 + 0];
    v.y = g[q * 4 + 1];
    v.z = g[q * 4 + 2];
    v.w = g[q * 4 + 3];
    p[q] = v;
  }
}

// ---------------------------------------------------------------------------
// K3: cross-B normalize, in place. Thread p owns (s,e) pair for all 8 b.
//   out[b,s,e] = masked[b,s,e] * capacity / (sum_b masked + eps)
// ---------------------------------------------------------------------------
__global__ __launch_bounds__(256) void k3_norm(float* __restrict__ buf) {
  const int p = blockIdx.x * 256 + threadIdx.x;  // (s,e) pair index
  if (p >= Sc * Ec) return;

  float v[8];
  float s = 0.f;
#pragma unroll
  for (int b = 0; b < 8; ++b) {
    v[b] = buf[(size_t)b * (Sc * Ec) + p];
    s += v[b];
  }
  const float scale = CAPACITY / (s + EPS);
#pragma unroll
  for (int b = 0; b < 8; ++b) {
    buf[(size_t)b * (Sc * Ec) + p] = v[b] * scale;
  }
}

// ---------------------------------------------------------------------------
extern "C" void kernel_launch(void* const* d_in, const int* in_sizes, int n_in,
                              void* d_out, int out_size, void* d_ws, size_t ws_size,
                              hipStream_t stream) {
  const float* X    = (const float*)d_in[0];  // [8,4096,2048]
  const float* W    = (const float*)d_in[1];  // [16,2048]
  const float* bias = (const float*)d_in[2];  // [16]
  float* out = (float*)d_out;                 // [8,4096,16] fp32, used as scratch too

  k1_logits<<<NBLK, 256, 0, stream>>>(X, W, out);
  k2_gate<<<NTOK / 256, 256, 0, stream>>>(out, bias);
  k3_norm<<<(Sc * Ec) / 256, 256, 0, stream>>>(out);
}

// Round 2
// 78.408 us; speedup vs baseline: 1.3910x; 1.3910x over previous
//
#include <hip/hip_runtime.h>

// Problem constants (fixed by reference setup_inputs)
constexpr int Bc = 8;
constexpr int Sc = 4096;
constexpr int Dc = 2048;
constexpr int Ec = 16;
constexpr int NTOK = Bc * Sc;            // 32768 tokens
constexpr int TOK_PER_BLK = 64;
constexpr int NBLK = NTOK / TOK_PER_BLK; // 512 blocks (2 per CU)
constexpr float EPS = 1e-6f;
constexpr float CAPACITY = 8.0f;         // int(1.0 * B)

// ---------------------------------------------------------------------------
// K1: logits[token][e] = dot(X[token], W[e]).  (bias added in K2)
// 4 waves/block; wave w owns experts 4w..4w+3, W held in 128 VGPRs/lane.
// X goes straight to VGPRs (no LDS): lane's share of token row is
// x[i] = X[tok][i*256 + lane*4 .. +3], i=0..7 — coalesced 1KB/instruction.
// All 4 waves read the same row ~concurrently -> L1 dedups; HBM sees X once.
// Two register buffers + 2-token interleave give ~2 compute bodies of
// prefetch distance with zero inline asm (compiler places the waitcnts).
// ---------------------------------------------------------------------------
__global__ __launch_bounds__(256, 2) void k1_logits(
    const float* __restrict__ X, const float* __restrict__ W,
    float* __restrict__ logits) {
  const int tid  = threadIdx.x;
  const int w    = tid >> 6;    // wave id 0..3 (uniform within wave)
  const int lane = tid & 63;
  const int e0   = w * 4;

  // W fragments: wreg[e_loc][i] covers d = i*256 + lane*4 + {0..3}
  float4 wreg[4][8];
#pragma unroll
  for (int e = 0; e < 4; ++e) {
#pragma unroll
    for (int i = 0; i < 8; ++i) {
      wreg[e][i] = *reinterpret_cast<const float4*>(
          W + (size_t)(e0 + e) * Dc + i * 256 + lane * 4);
    }
  }

  const int tok0 = blockIdx.x * TOK_PER_BLK;
  const float* xbase = X + (size_t)tok0 * Dc + lane * 4;

  float4 xa[8], xb[8];

#define LOAD_BUF(buf, t)                                                      \
  {                                                                           \
    const float* p_ = xbase + (size_t)(t)*Dc;                                 \
    _Pragma("unroll") for (int i_ = 0; i_ < 8; ++i_) {                        \
      buf[i_] = *reinterpret_cast<const float4*>(p_ + i_ * 256);              \
    }                                                                         \
  }

#define COMPUTE_STORE(buf, t)                                                 \
  {                                                                           \
    float a0 = 0.f, a1 = 0.f, a2 = 0.f, a3 = 0.f;                             \
    _Pragma("unroll") for (int i_ = 0; i_ < 8; ++i_) {                        \
      const float4 xv = buf[i_];                                              \
      a0 = fmaf(xv.x, wreg[0][i_].x, a0);                                     \
      a0 = fmaf(xv.y, wreg[0][i_].y, a0);                                     \
      a0 = fmaf(xv.z, wreg[0][i_].z, a0);                                     \
      a0 = fmaf(xv.w, wreg[0][i_].w, a0);                                     \
      a1 = fmaf(xv.x, wreg[1][i_].x, a1);                                     \
      a1 = fmaf(xv.y, wreg[1][i_].y, a1);                                     \
      a1 = fmaf(xv.z, wreg[1][i_].z, a1);                                     \
      a1 = fmaf(xv.w, wreg[1][i_].w, a1);                                     \
      a2 = fmaf(xv.x, wreg[2][i_].x, a2);                                     \
      a2 = fmaf(xv.y, wreg[2][i_].y, a2);                                     \
      a2 = fmaf(xv.z, wreg[2][i_].z, a2);                                     \
      a2 = fmaf(xv.w, wreg[2][i_].w, a2);                                     \
      a3 = fmaf(xv.x, wreg[3][i_].x, a3);                                     \
      a3 = fmaf(xv.y, wreg[3][i_].y, a3);                                     \
      a3 = fmaf(xv.z, wreg[3][i_].z, a3);                                     \
      a3 = fmaf(xv.w, wreg[3][i_].w, a3);                                     \
    }                                                                         \
    _Pragma("unroll") for (int m_ = 32; m_ >= 1; m_ >>= 1) {                  \
      a0 += __shfl_xor(a0, m_, 64);                                           \
      a1 += __shfl_xor(a1, m_, 64);                                           \
      a2 += __shfl_xor(a2, m_, 64);                                           \
      a3 += __shfl_xor(a3, m_, 64);                                           \
    }                                                                         \
    if (lane == 0) {                                                          \
      float4 r_;                                                              \
      r_.x = a0; r_.y = a1; r_.z = a2; r_.w = a3;                             \
      *reinterpret_cast<float4*>(logits + (size_t)(tok0 + (t)) * Ec + e0) = r_;\
    }                                                                         \
  }

  LOAD_BUF(xa, 0)
  LOAD_BUF(xb, 1)

#pragma unroll 1
  for (int t = 0; t < TOK_PER_BLK; t += 2) {
    COMPUTE_STORE(xa, t)
    if (t + 2 < TOK_PER_BLK) LOAD_BUF(xa, t + 2)
    COMPUTE_STORE(xb, t + 1)
    if (t + 3 < TOK_PER_BLK) LOAD_BUF(xb, t + 3)
  }

#undef LOAD_BUF
#undef COMPUTE_STORE
}

// ---------------------------------------------------------------------------
// K2: per token, in place on buf (= d_out):
//   l = logits + bias; gate = softmax(l); mask = top-8 of l (ties -> lower
//   index, matching jax.lax.top_k); buf <- gate * mask
// ---------------------------------------------------------------------------
__global__ __launch_bounds__(256) void k2_gate(float* __restrict__ buf,
                                               const float* __restrict__ bias) {
  const int t = blockIdx.x * 256 + threadIdx.x;
  if (t >= NTOK) return;

  float4* p = reinterpret_cast<float4*>(buf + (size_t)t * Ec);
  float l[16];
#pragma unroll
  for (int q = 0; q < 4; ++q) {
    const float4 v = p[q];
    l[q * 4 + 0] = v.x;
    l[q * 4 + 1] = v.y;
    l[q * 4 + 2] = v.z;
    l[q * 4 + 3] = v.w;
  }
#pragma unroll
  for (int i = 0; i < 16; ++i) l[i] += bias[i];

  float m = l[0];
#pragma unroll
  for (int i = 1; i < 16; ++i) m = fmaxf(m, l[i]);

  float ex[16];
  float Z = 0.f;
#pragma unroll
  for (int i = 0; i < 16; ++i) {
    ex[i] = expf(l[i] - m);
    Z += ex[i];
  }
  const float invZ = 1.0f / Z;

  float g[16];
#pragma unroll
  for (int i = 0; i < 16; ++i) {
    int cnt = 0;
#pragma unroll
    for (int j = 0; j < 16; ++j) {
      cnt += (l[j] > l[i]) || ((l[j] == l[i]) && (j < i));
    }
    g[i] = (cnt < 8) ? ex[i] * invZ : 0.0f;
  }

#pragma unroll
  for (int q = 0; q < 4; ++q) {
    float4 v;
    v.x = g[q * 4 + 0];
    v.y = g[q * 4 + 1];
    v.z = g[q * 4 + 2];
    v.w = g[q * 4 + 3];
    p[q] = v;
  }
}

// ---------------------------------------------------------------------------
// K3: cross-B normalize, in place. Thread p owns (s,e) pair for all 8 b.
//   out[b,s,e] = masked[b,s,e] * capacity / (sum_b masked + eps)
// ---------------------------------------------------------------------------
__global__ __launch_bounds__(256) void k3_norm(float* __restrict__ buf) {
  const int p = blockIdx.x * 256 + threadIdx.x;  // (s,e) pair index
  if (p >= Sc * Ec) return;

  float v[8];
  float s = 0.f;
#pragma unroll
  for (int b = 0; b < 8; ++b) {
    v[b] = buf[(size_t)b * (Sc * Ec) + p];
    s += v[b];
  }
  const float scale = CAPACITY / (s + EPS);
#pragma unroll
  for (int b = 0; b < 8; ++b) {
    buf[(size_t)b * (Sc * Ec) + p] = v[b] * scale;
  }
}

// ---------------------------------------------------------------------------
extern "C" void kernel_launch(void* const* d_in, const int* in_sizes, int n_in,
                              void* d_out, int out_size, void* d_ws, size_t ws_size,
                              hipStream_t stream) {
  const float* X    = (const float*)d_in[0];  // [8,4096,2048]
  const float* W    = (const float*)d_in[1];  // [16,2048]
  const float* bias = (const float*)d_in[2];  // [16]
  float* out = (float*)d_out;                 // [8,4096,16] fp32, used as scratch too

  k1_logits<<<NBLK, 256, 0, stream>>>(X, W, out);
  k2_gate<<<NTOK / 256, 256, 0, stream>>>(out, bias);
  k3_norm<<<(Sc * Ec) / 256, 256, 0, stream>>>(out);
}

// Round 3
// 63.538 us; speedup vs baseline: 1.7165x; 1.2340x over previous
//
#include <hip/hip_runtime.h>

// Problem constants (fixed by reference setup_inputs)
constexpr int Bc = 8;
constexpr int Sc = 4096;
constexpr int Dc = 2048;
constexpr int Ec = 16;
constexpr int NTOK = Bc * Sc;            // 32768 tokens
constexpr int TOK_PER_BLK = 64;
constexpr int NBLK = NTOK / TOK_PER_BLK; // 512 blocks (2 per CU)
constexpr float EPS = 1e-6f;
constexpr float CAPACITY = 8.0f;         // int(1.0 * B)

// ---------------------------------------------------------------------------
// K1: logits[token][e] = dot(X[token], W[e]).  (bias added in K2)
// 4 waves/block; wave w owns experts 4w..4w+3, W held in 128 VGPRs/lane.
// X straight to VGPRs: lane's share of a token row is
// x[i] = X[tok][i*256 + lane*4 .. +3], i=0..7 — coalesced 1KB/instruction.
// All 4 waves read the same row ~concurrently -> L1 dedups; HBM sees X once.
// THREE register buffers: load for t+3 issues 2 compute bodies before use
// (~1400 effective cycles with 2 waves/SIMD) — covers ~900-cyc HBM latency.
// Cross-lane reduce: value-merging butterfly, 7 shfl total for 4 experts.
// ---------------------------------------------------------------------------
__global__ __launch_bounds__(256, 2) void k1_logits(
    const float* __restrict__ X, const float* __restrict__ W,
    float* __restrict__ logits) {
  const int tid  = threadIdx.x;
  const int w    = tid >> 6;    // wave id 0..3 (uniform within wave)
  const int lane = tid & 63;
  const int e0   = w * 4;

  // W fragments: wreg[e_loc][i] covers d = i*256 + lane*4 + {0..3}
  float4 wreg[4][8];
#pragma unroll
  for (int e = 0; e < 4; ++e) {
#pragma unroll
    for (int i = 0; i < 8; ++i) {
      wreg[e][i] = *reinterpret_cast<const float4*>(
          W + (size_t)(e0 + e) * Dc + i * 256 + lane * 4);
    }
  }

  const int tok0 = blockIdx.x * TOK_PER_BLK;
  const float* xbase = X + (size_t)tok0 * Dc + lane * 4;
  float* lbase = logits + (size_t)tok0 * Ec + e0 + lane;  // lane<4 stores

  float4 xa[8], xb[8], xc[8];

#define LOAD_BUF(buf, t)                                                      \
  {                                                                           \
    const float* p_ = xbase + (size_t)(t)*Dc;                                 \
    _Pragma("unroll") for (int i_ = 0; i_ < 8; ++i_) {                        \
      buf[i_] = *reinterpret_cast<const float4*>(p_ + i_ * 256);              \
    }                                                                         \
  }

#define COMPUTE_STORE(buf, t)                                                 \
  {                                                                           \
    float a0 = 0.f, a1 = 0.f, a2 = 0.f, a3 = 0.f;                             \
    _Pragma("unroll") for (int i_ = 0; i_ < 8; ++i_) {                        \
      const float4 xv = buf[i_];                                              \
      a0 = fmaf(xv.x, wreg[0][i_].x, a0);                                     \
      a0 = fmaf(xv.y, wreg[0][i_].y, a0);                                     \
      a0 = fmaf(xv.z, wreg[0][i_].z, a0);                                     \
      a0 = fmaf(xv.w, wreg[0][i_].w, a0);                                     \
      a1 = fmaf(xv.x, wreg[1][i_].x, a1);                                     \
      a1 = fmaf(xv.y, wreg[1][i_].y, a1);                                     \
      a1 = fmaf(xv.z, wreg[1][i_].z, a1);                                     \
      a1 = fmaf(xv.w, wreg[1][i_].w, a1);                                     \
      a2 = fmaf(xv.x, wreg[2][i_].x, a2);                                     \
      a2 = fmaf(xv.y, wreg[2][i_].y, a2);                                     \
      a2 = fmaf(xv.z, wreg[2][i_].z, a2);                                     \
      a2 = fmaf(xv.w, wreg[2][i_].w, a2);                                     \
      a3 = fmaf(xv.x, wreg[3][i_].x, a3);                                     \
      a3 = fmaf(xv.y, wreg[3][i_].y, a3);                                     \
      a3 = fmaf(xv.z, wreg[3][i_].z, a3);                                     \
      a3 = fmaf(xv.w, wreg[3][i_].w, a3);                                     \
    }                                                                         \
    /* value-merging butterfly: 7 shfl for 4 experts */                       \
    const bool o1 = (lane & 1) != 0;                                          \
    float s01 = o1 ? a0 : a1;                                                 \
    float r01 = __shfl_xor(s01, 1, 64);                                       \
    float b0v = o1 ? (a1 + r01) : (a0 + r01);                                 \
    float s23 = o1 ? a2 : a3;                                                 \
    float r23 = __shfl_xor(s23, 1, 64);                                       \
    float b1v = o1 ? (a3 + r23) : (a2 + r23);                                 \
    const bool o2 = (lane & 2) != 0;                                          \
    float sq = o2 ? b0v : b1v;                                                \
    float rq = __shfl_xor(sq, 2, 64);                                         \
    float cq = o2 ? (b1v + rq) : (b0v + rq);                                  \
    cq += __shfl_xor(cq, 4, 64);                                              \
    cq += __shfl_xor(cq, 8, 64);                                              \
    cq += __shfl_xor(cq, 16, 64);                                             \
    cq += __shfl_xor(cq, 32, 64);                                             \
    if (lane < 4) lbase[(size_t)(t)*Ec] = cq;                                 \
  }

  // prologue: fill the 3-deep pipeline
  LOAD_BUF(xa, 0)
  LOAD_BUF(xb, 1)
  LOAD_BUF(xc, 2)

  // steady state: t = 0,3,...,57 (loads reach token 62, computes reach 59)
#pragma unroll 1
  for (int t = 0; t < TOK_PER_BLK - 6; t += 3) {
    COMPUTE_STORE(xa, t)
    LOAD_BUF(xa, t + 3)
    COMPUTE_STORE(xb, t + 1)
    LOAD_BUF(xb, t + 4)
    COMPUTE_STORE(xc, t + 2)
    LOAD_BUF(xc, t + 5)
  }
  // epilogue: tokens 60..63
  COMPUTE_STORE(xa, 60)
  LOAD_BUF(xa, 63)
  COMPUTE_STORE(xb, 61)
  COMPUTE_STORE(xc, 62)
  COMPUTE_STORE(xa, 63)

#undef LOAD_BUF
#undef COMPUTE_STORE
}

// ---------------------------------------------------------------------------
// K2: per token, in place on buf (= d_out):
//   l = logits + bias; gate = softmax(l); mask = top-8 of l (ties -> lower
//   index, matching jax.lax.top_k); buf <- gate * mask
// ---------------------------------------------------------------------------
__global__ __launch_bounds__(256) void k2_gate(float* __restrict__ buf,
                                               const float* __restrict__ bias) {
  const int t = blockIdx.x * 256 + threadIdx.x;
  if (t >= NTOK) return;

  float4* p = reinterpret_cast<float4*>(buf + (size_t)t * Ec);
  float l[16];
#pragma unroll
  for (int q = 0; q < 4; ++q) {
    const float4 v = p[q];
    l[q * 4 + 0] = v.x;
    l[q * 4 + 1] = v.y;
    l[q * 4 + 2] = v.z;
    l[q * 4 + 3] = v.w;
  }
#pragma unroll
  for (int i = 0; i < 16; ++i) l[i] += bias[i];

  float m = l[0];
#pragma unroll
  for (int i = 1; i < 16; ++i) m = fmaxf(m, l[i]);

  float ex[16];
  float Z = 0.f;
#pragma unroll
  for (int i = 0; i < 16; ++i) {
    ex[i] = expf(l[i] - m);
    Z += ex[i];
  }
  const float invZ = 1.0f / Z;

  float g[16];
#pragma unroll
  for (int i = 0; i < 16; ++i) {
    int cnt = 0;
#pragma unroll
    for (int j = 0; j < 16; ++j) {
      cnt += (l[j] > l[i]) || ((l[j] == l[i]) && (j < i));
    }
    g[i] = (cnt < 8) ? ex[i] * invZ : 0.0f;
  }

#pragma unroll
  for (int q = 0; q < 4; ++q) {
    float4 v;
    v.x = g[q * 4 + 0];
    v.y = g[q * 4 + 1];
    v.z = g[q * 4 + 2];
    v.w = g[q * 4 + 3];
    p[q] = v;
  }
}

// ---------------------------------------------------------------------------
// K3: cross-B normalize, in place. Thread p owns (s,e) pair for all 8 b.
//   out[b,s,e] = masked[b,s,e] * capacity / (sum_b masked + eps)
// ---------------------------------------------------------------------------
__global__ __launch_bounds__(256) void k3_norm(float* __restrict__ buf) {
  const int p = blockIdx.x * 256 + threadIdx.x;  // (s,e) pair index
  if (p >= Sc * Ec) return;

  float v[8];
  float s = 0.f;
#pragma unroll
  for (int b = 0; b < 8; ++b) {
    v[b] = buf[(size_t)b * (Sc * Ec) + p];
    s += v[b];
  }
  const float scale = CAPACITY / (s + EPS);
#pragma unroll
  for (int b = 0; b < 8; ++b) {
    buf[(size_t)b * (Sc * Ec) + p] = v[b] * scale;
  }
}

// ---------------------------------------------------------------------------
extern "C" void kernel_launch(void* const* d_in, const int* in_sizes, int n_in,
                              void* d_out, int out_size, void* d_ws, size_t ws_size,
                              hipStream_t stream) {
  const float* X    = (const float*)d_in[0];  // [8,4096,2048]
  const float* W    = (const float*)d_in[1];  // [16,2048]
  const float* bias = (const float*)d_in[2];  // [16]
  float* out = (float*)d_out;                 // [8,4096,16] fp32, used as scratch too

  k1_logits<<<NBLK, 256, 0, stream>>>(X, W, out);
  k2_gate<<<NTOK / 256, 256, 0, stream>>>(out, bias);
  k3_norm<<<(Sc * Ec) / 256, 256, 0, stream>>>(out);
}

// Round 4
// 58.673 us; speedup vs baseline: 1.8589x; 1.0829x over previous
//
#include <hip/hip_runtime.h>

// Problem constants (fixed by reference setup_inputs)
constexpr int Bc = 8;
constexpr int Sc = 4096;
constexpr int Dc = 2048;
constexpr int Ec = 16;
constexpr int NTOK = Bc * Sc;            // 32768 tokens
constexpr int TOK_PER_BLK = 64;
constexpr int NBLK = NTOK / TOK_PER_BLK; // 512 blocks (2 per CU at 8 waves)
constexpr float EPS = 1e-6f;
constexpr float CAPACITY = 8.0f;         // int(1.0 * B)

// ---------------------------------------------------------------------------
// K1 (fused logits + gate):
//   8 waves/block (512 thr). Wave w: quarter q = w>>1 of D (512 floats),
//   expert octet g = w&1 (experts 8g..8g+7). W slice in 64 VGPR/lane;
//   X slice (512 floats) loaded straight to 2 float4/lane -> ~105 VGPR total
//   => 4 waves/SIMD (2x the occupancy of the previous 4-expert/full-D wave).
//   Depth-3 register pipeline; value-merging butterfly (10 shfl / 8 experts);
//   partial logits -> padded LDS; ONE barrier; then 8 thr/token compute
//   softmax + top-8 mask in-register and store masked scores to d_out.
// ---------------------------------------------------------------------------
__global__ __launch_bounds__(512, 4) void k1_fused(
    const float* __restrict__ X, const float* __restrict__ W,
    const float* __restrict__ bias, float* __restrict__ out) {
  // partial logits, padded: stride 20 floats => token index spreads over
  // 8 distinct banks for the gate-phase read pattern (t*20 mod 32)
  __shared__ float plds[4][TOK_PER_BLK][20];  // 20 KB
  __shared__ float bias_lds[Ec];

  const int tid  = threadIdx.x;
  const int w    = tid >> 6;    // wave 0..7
  const int lane = tid & 63;
  const int q    = w >> 1;      // D-quarter 0..3
  const int g    = w & 1;       // expert octet
  const int eg0  = g * 8;

  if (tid < Ec) bias_lds[tid] = bias[tid];

  // W fragments: wreg[j][i] covers expert eg0+j, d = q*512 + i*256 + lane*4
  float4 wreg[8][2];
#pragma unroll
  for (int j = 0; j < 8; ++j) {
#pragma unroll
    for (int i = 0; i < 2; ++i) {
      wreg[j][i] = *reinterpret_cast<const float4*>(
          W + (size_t)(eg0 + j) * Dc + q * 512 + i * 256 + lane * 4);
    }
  }

  const int tok0 = blockIdx.x * TOK_PER_BLK;
  const float* xbase = X + (size_t)tok0 * Dc + q * 512 + lane * 4;

  float4 xa[2], xb[2], xc[2];

#define LOAD_BUF(buf, t)                                                      \
  {                                                                           \
    const float* p_ = xbase + (size_t)(t)*Dc;                                 \
    buf[0] = *reinterpret_cast<const float4*>(p_);                            \
    buf[1] = *reinterpret_cast<const float4*>(p_ + 256);                      \
  }

#define COMPUTE_STORE(buf, t)                                                 \
  {                                                                           \
    float a0 = 0.f, a1 = 0.f, a2 = 0.f, a3 = 0.f;                             \
    float a4 = 0.f, a5 = 0.f, a6 = 0.f, a7 = 0.f;                             \
    _Pragma("unroll") for (int i_ = 0; i_ < 2; ++i_) {                        \
      const float4 xv = buf[i_];                                              \
      a0 = fmaf(xv.x, wreg[0][i_].x, a0);                                     \
      a0 = fmaf(xv.y, wreg[0][i_].y, a0);                                     \
      a0 = fmaf(xv.z, wreg[0][i_].z, a0);                                     \
      a0 = fmaf(xv.w, wreg[0][i_].w, a0);                                     \
      a1 = fmaf(xv.x, wreg[1][i_].x, a1);                                     \
      a1 = fmaf(xv.y, wreg[1][i_].y, a1);                                     \
      a1 = fmaf(xv.z, wreg[1][i_].z, a1);                                     \
      a1 = fmaf(xv.w, wreg[1][i_].w, a1);                                     \
      a2 = fmaf(xv.x, wreg[2][i_].x, a2);                                     \
      a2 = fmaf(xv.y, wreg[2][i_].y, a2);                                     \
      a2 = fmaf(xv.z, wreg[2][i_].z, a2);                                     \
      a2 = fmaf(xv.w, wreg[2][i_].w, a2);                                     \
      a3 = fmaf(xv.x, wreg[3][i_].x, a3);                                     \
      a3 = fmaf(xv.y, wreg[3][i_].y, a3);                                     \
      a3 = fmaf(xv.z, wreg[3][i_].z, a3);                                     \
      a3 = fmaf(xv.w, wreg[3][i_].w, a3);                                     \
      a4 = fmaf(xv.x, wreg[4][i_].x, a4);                                     \
      a4 = fmaf(xv.y, wreg[4][i_].y, a4);                                     \
      a4 = fmaf(xv.z, wreg[4][i_].z, a4);                                     \
      a4 = fmaf(xv.w, wreg[4][i_].w, a4);                                     \
      a5 = fmaf(xv.x, wreg[5][i_].x, a5);                                     \
      a5 = fmaf(xv.y, wreg[5][i_].y, a5);                                     \
      a5 = fmaf(xv.z, wreg[5][i_].z, a5);                                     \
      a5 = fmaf(xv.w, wreg[5][i_].w, a5);                                     \
      a6 = fmaf(xv.x, wreg[6][i_].x, a6);                                     \
      a6 = fmaf(xv.y, wreg[6][i_].y, a6);                                     \
      a6 = fmaf(xv.z, wreg[6][i_].z, a6);                                     \
      a6 = fmaf(xv.w, wreg[6][i_].w, a6);                                     \
      a7 = fmaf(xv.x, wreg[7][i_].x, a7);                                     \
      a7 = fmaf(xv.y, wreg[7][i_].y, a7);                                     \
      a7 = fmaf(xv.z, wreg[7][i_].z, a7);                                     \
      a7 = fmaf(xv.w, wreg[7][i_].w, a7);                                     \
    }                                                                         \
    /* value-merging butterfly: 10 shfl reduce 8 accs over 64 lanes;     */   \
    /* after it, lane l holds full quarter-sum of expert eg0 + (l&7).    */   \
    const bool o1 = (lane & 1) != 0;                                          \
    float b0, b1, b2, b3;                                                     \
    { float s_ = o1 ? a0 : a1; float r_ = __shfl_xor(s_, 1, 64);              \
      b0 = o1 ? (a1 + r_) : (a0 + r_); }                                      \
    { float s_ = o1 ? a2 : a3; float r_ = __shfl_xor(s_, 1, 64);              \
      b1 = o1 ? (a3 + r_) : (a2 + r_); }                                      \
    { float s_ = o1 ? a4 : a5; float r_ = __shfl_xor(s_, 1, 64);              \
      b2 = o1 ? (a5 + r_) : (a4 + r_); }                                      \
    { float s_ = o1 ? a6 : a7; float r_ = __shfl_xor(s_, 1, 64);              \
      b3 = o1 ? (a7 + r_) : (a6 + r_); }                                      \
    const bool o2 = (lane & 2) != 0;                                          \
    float c0, c1;                                                             \
    { float s_ = o2 ? b0 : b1; float r_ = __shfl_xor(s_, 2, 64);              \
      c0 = o2 ? (b1 + r_) : (b0 + r_); }                                      \
    { float s_ = o2 ? b2 : b3; float r_ = __shfl_xor(s_, 2, 64);              \
      c1 = o2 ? (b3 + r_) : (b2 + r_); }                                      \
    const bool o4 = (lane & 4) != 0;                                          \
    float dv;                                                                 \
    { float s_ = o4 ? c0 : c1; float r_ = __shfl_xor(s_, 4, 64);              \
      dv = o4 ? (c1 + r_) : (c0 + r_); }                                      \
    dv += __shfl_xor(dv, 8, 64);                                              \
    dv += __shfl_xor(dv, 16, 64);                                             \
    dv += __shfl_xor(dv, 32, 64);                                             \
    if (lane < 8) plds[q][t][eg0 + lane] = dv;                                \
  }

  // prologue: fill the 3-deep pipeline
  LOAD_BUF(xa, 0)
  LOAD_BUF(xb, 1)
  LOAD_BUF(xc, 2)

#pragma unroll 1
  for (int t = 0; t < TOK_PER_BLK - 6; t += 3) {
    COMPUTE_STORE(xa, t)
    LOAD_BUF(xa, t + 3)
    COMPUTE_STORE(xb, t + 1)
    LOAD_BUF(xb, t + 4)
    COMPUTE_STORE(xc, t + 2)
    LOAD_BUF(xc, t + 5)
  }
  // epilogue: tokens 60..63
  COMPUTE_STORE(xa, 60)
  LOAD_BUF(xa, 63)
  COMPUTE_STORE(xb, 61)
  COMPUTE_STORE(xc, 62)
  COMPUTE_STORE(xa, 63)

#undef LOAD_BUF
#undef COMPUTE_STORE

  __syncthreads();

  // ---- fused gate phase: 8 threads per token, each owns 2 experts ----
  {
    const int t = tid >> 3;   // token 0..63
    const int j = tid & 7;    // expert pair index

    float l[16];
#pragma unroll
    for (int i = 0; i < 16; ++i) {
      l[i] = plds[0][t][i] + plds[1][t][i] + plds[2][t][i] + plds[3][t][i] +
             bias_lds[i];
    }

    float m = l[0];
#pragma unroll
    for (int i = 1; i < 16; ++i) m = fmaxf(m, l[i]);

    float ex[16];
    float Z = 0.f;
#pragma unroll
    for (int i = 0; i < 16; ++i) {
      ex[i] = __expf(l[i] - m);
      Z += ex[i];
    }
    const float invZ = 1.0f / Z;

    // top-8 mask via rank count (ties -> lower index, matches lax.top_k)
    float2 r;
    {
      const int i0 = 2 * j;
      int c0 = 0, c1 = 0;
#pragma unroll
      for (int k = 0; k < 16; ++k) {
        c0 += (l[k] > l[i0]) || ((l[k] == l[i0]) && (k < i0));
        c1 += (l[k] > l[i0 + 1]) || ((l[k] == l[i0 + 1]) && (k < i0 + 1));
      }
      r.x = (c0 < 8) ? ex[i0] * invZ : 0.0f;
      r.y = (c1 < 8) ? ex[i0 + 1] * invZ : 0.0f;
    }
    *reinterpret_cast<float2*>(out + (size_t)(tok0 + t) * Ec + 2 * j) = r;
  }
}

// ---------------------------------------------------------------------------
// K3: cross-B normalize, in place. Thread p owns (s,e) pair for all 8 b.
//   out[b,s,e] = masked[b,s,e] * capacity / (sum_b masked + eps)
// ---------------------------------------------------------------------------
__global__ __launch_bounds__(256) void k3_norm(float* __restrict__ buf) {
  const int p = blockIdx.x * 256 + threadIdx.x;  // (s,e) pair index
  if (p >= Sc * Ec) return;

  float v[8];
  float s = 0.f;
#pragma unroll
  for (int b = 0; b < 8; ++b) {
    v[b] = buf[(size_t)b * (Sc * Ec) + p];
    s += v[b];
  }
  const float scale = CAPACITY / (s + EPS);
#pragma unroll
  for (int b = 0; b < 8; ++b) {
    buf[(size_t)b * (Sc * Ec) + p] = v[b] * scale;
  }
}

// ---------------------------------------------------------------------------
extern "C" void kernel_launch(void* const* d_in, const int* in_sizes, int n_in,
                              void* d_out, int out_size, void* d_ws, size_t ws_size,
                              hipStream_t stream) {
  const float* X    = (const float*)d_in[0];  // [8,4096,2048]
  const float* W    = (const float*)d_in[1];  // [16,2048]
  const float* bias = (const float*)d_in[2];  // [16]
  float* out = (float*)d_out;                 // [8,4096,16] fp32

  k1_fused<<<NBLK, 512, 0, stream>>>(X, W, bias, out);
  k3_norm<<<(Sc * Ec) / 256, 256, 0, stream>>>(out);
}

// Round 5
// 57.024 us; speedup vs baseline: 1.9126x; 1.0289x over previous
//
#include <hip/hip_runtime.h>

// Problem constants (fixed by reference setup_inputs)
constexpr int Bc = 8;
constexpr int Sc = 4096;
constexpr int Dc = 2048;
constexpr int Ec = 16;
constexpr int S_PER_BLK = 8;             // s-values per block
constexpr int TOK_PER_BLK = Bc * S_PER_BLK;  // 64 tokens (all 8 b's x 8 s)
constexpr int NBLK = Sc / S_PER_BLK;     // 512 blocks (2 per CU)
constexpr float EPS = 1e-6f;
constexpr float CAPACITY = 8.0f;         // int(1.0 * B)

// ---------------------------------------------------------------------------
// Fully fused SwitchGate kernel.
//   Block owns s in [8*bid, 8*bid+8) for ALL 8 batch rows -> the cross-B
//   denominator is block-local and the whole op is one kernel, one launch.
//   Token-local index t = b*8 + s_loc.
//
//   Phase 1 (logits): 8 waves. Wave w: D-quarter q=w>>1 (512 floats),
//   expert octet g=w&1. W slice in 64 VGPR/lane; X slice direct to VGPRs,
//   depth-3 register pipeline; value-merging butterfly (10 shfl / 8 experts);
//   partial logits -> padded LDS.
//   Phase 2 (gate): 8 thr/token: combine quarters + bias, softmax, top-8
//   mask (rank count, ties->lower idx = lax.top_k), masked scores -> LDS.
//   Phase 3 (normalize): thread (b, s_loc, expert-pair) sums masked over b,
//   scales, writes final float2 -> d_out. Coalesced 512B/wave segments.
// ---------------------------------------------------------------------------
__global__ __launch_bounds__(512, 4) void k_switchgate(
    const float* __restrict__ X, const float* __restrict__ W,
    const float* __restrict__ bias, float* __restrict__ out) {
  __shared__ float plds[4][TOK_PER_BLK][20];   // 20 KB partial logits
  __shared__ float masked[TOK_PER_BLK][18];    // 4.5 KB masked scores
  __shared__ float bias_lds[Ec];

  const int tid  = threadIdx.x;
  const int w    = tid >> 6;    // wave 0..7
  const int lane = tid & 63;
  const int q    = w >> 1;      // D-quarter 0..3
  const int g    = w & 1;       // expert octet
  const int eg0  = g * 8;

  if (tid < Ec) bias_lds[tid] = bias[tid];

  // W fragments: wreg[j][i] covers expert eg0+j, d = q*512 + i*256 + lane*4
  float4 wreg[8][2];
#pragma unroll
  for (int j = 0; j < 8; ++j) {
#pragma unroll
    for (int i = 0; i < 2; ++i) {
      wreg[j][i] = *reinterpret_cast<const float4*>(
          W + (size_t)(eg0 + j) * Dc + q * 512 + i * 256 + lane * 4);
    }
  }

  const int s0 = blockIdx.x * S_PER_BLK;
  // token t (= b*8 + s_loc) row offset: b*Sc*Dc + (s0 + s_loc)*Dc
  const float* xbase = X + (size_t)s0 * Dc + q * 512 + lane * 4;

  float4 xa[2], xb[2], xc[2];

#define LOAD_BUF(buf, t)                                                      \
  {                                                                           \
    const float* p_ = xbase + (size_t)((t) >> 3) * (Sc * (size_t)Dc) +        \
                      (size_t)((t) & 7) * Dc;                                 \
    buf[0] = *reinterpret_cast<const float4*>(p_);                            \
    buf[1] = *reinterpret_cast<const float4*>(p_ + 256);                      \
  }

#define COMPUTE_STORE(buf, t)                                                 \
  {                                                                           \
    float a0 = 0.f, a1 = 0.f, a2 = 0.f, a3 = 0.f;                             \
    float a4 = 0.f, a5 = 0.f, a6 = 0.f, a7 = 0.f;                             \
    _Pragma("unroll") for (int i_ = 0; i_ < 2; ++i_) {                        \
      const float4 xv = buf[i_];                                              \
      a0 = fmaf(xv.x, wreg[0][i_].x, a0);                                     \
      a0 = fmaf(xv.y, wreg[0][i_].y, a0);                                     \
      a0 = fmaf(xv.z, wreg[0][i_].z, a0);                                     \
      a0 = fmaf(xv.w, wreg[0][i_].w, a0);                                     \
      a1 = fmaf(xv.x, wreg[1][i_].x, a1);                                     \
      a1 = fmaf(xv.y, wreg[1][i_].y, a1);                                     \
      a1 = fmaf(xv.z, wreg[1][i_].z, a1);                                     \
      a1 = fmaf(xv.w, wreg[1][i_].w, a1);                                     \
      a2 = fmaf(xv.x, wreg[2][i_].x, a2);                                     \
      a2 = fmaf(xv.y, wreg[2][i_].y, a2);                                     \
      a2 = fmaf(xv.z, wreg[2][i_].z, a2);                                     \
      a2 = fmaf(xv.w, wreg[2][i_].w, a2);                                     \
      a3 = fmaf(xv.x, wreg[3][i_].x, a3);                                     \
      a3 = fmaf(xv.y, wreg[3][i_].y, a3);                                     \
      a3 = fmaf(xv.z, wreg[3][i_].z, a3);                                     \
      a3 = fmaf(xv.w, wreg[3][i_].w, a3);                                     \
      a4 = fmaf(xv.x, wreg[4][i_].x, a4);                                     \
      a4 = fmaf(xv.y, wreg[4][i_].y, a4);                                     \
      a4 = fmaf(xv.z, wreg[4][i_].z, a4);                                     \
      a4 = fmaf(xv.w, wreg[4][i_].w, a4);                                     \
      a5 = fmaf(xv.x, wreg[5][i_].x, a5);                                     \
      a5 = fmaf(xv.y, wreg[5][i_].y, a5);                                     \
      a5 = fmaf(xv.z, wreg[5][i_].z, a5);                                     \
      a5 = fmaf(xv.w, wreg[5][i_].w, a5);                                     \
      a6 = fmaf(xv.x, wreg[6][i_].x, a6);                                     \
      a6 = fmaf(xv.y, wreg[6][i_].y, a6);                                     \
      a6 = fmaf(xv.z, wreg[6][i_].z, a6);                                     \
      a6 = fmaf(xv.w, wreg[6][i_].w, a6);                                     \
      a7 = fmaf(xv.x, wreg[7][i_].x, a7);                                     \
      a7 = fmaf(xv.y, wreg[7][i_].y, a7);                                     \
      a7 = fmaf(xv.z, wreg[7][i_].z, a7);                                     \
      a7 = fmaf(xv.w, wreg[7][i_].w, a7);                                     \
    }                                                                         \
    /* value-merging butterfly: 10 shfl; lane l -> expert eg0+(l&7) */        \
    const bool o1 = (lane & 1) != 0;                                          \
    float b0, b1, b2, b3;                                                     \
    { float s_ = o1 ? a0 : a1; float r_ = __shfl_xor(s_, 1, 64);              \
      b0 = o1 ? (a1 + r_) : (a0 + r_); }                                      \
    { float s_ = o1 ? a2 : a3; float r_ = __shfl_xor(s_, 1, 64);              \
      b1 = o1 ? (a3 + r_) : (a2 + r_); }                                      \
    { float s_ = o1 ? a4 : a5; float r_ = __shfl_xor(s_, 1, 64);              \
      b2 = o1 ? (a5 + r_) : (a4 + r_); }                                      \
    { float s_ = o1 ? a6 : a7; float r_ = __shfl_xor(s_, 1, 64);              \
      b3 = o1 ? (a7 + r_) : (a6 + r_); }                                      \
    const bool o2 = (lane & 2) != 0;                                          \
    float c0, c1;                                                             \
    { float s_ = o2 ? b0 : b1; float r_ = __shfl_xor(s_, 2, 64);              \
      c0 = o2 ? (b1 + r_) : (b0 + r_); }                                      \
    { float s_ = o2 ? b2 : b3; float r_ = __shfl_xor(s_, 2, 64);              \
      c1 = o2 ? (b3 + r_) : (b2 + r_); }                                      \
    const bool o4 = (lane & 4) != 0;                                          \
    float dv;                                                                 \
    { float s_ = o4 ? c0 : c1; float r_ = __shfl_xor(s_, 4, 64);              \
      dv = o4 ? (c1 + r_) : (c0 + r_); }                                      \
    dv += __shfl_xor(dv, 8, 64);                                              \
    dv += __shfl_xor(dv, 16, 64);                                             \
    dv += __shfl_xor(dv, 32, 64);                                             \
    if (lane < 8) plds[q][t][eg0 + lane] = dv;                                \
  }

  // prologue: fill the 3-deep pipeline
  LOAD_BUF(xa, 0)
  LOAD_BUF(xb, 1)
  LOAD_BUF(xc, 2)

#pragma unroll 1
  for (int t = 0; t < TOK_PER_BLK - 6; t += 3) {
    COMPUTE_STORE(xa, t)
    LOAD_BUF(xa, t + 3)
    COMPUTE_STORE(xb, t + 1)
    LOAD_BUF(xb, t + 4)
    COMPUTE_STORE(xc, t + 2)
    LOAD_BUF(xc, t + 5)
  }
  // epilogue: tokens 60..63
  COMPUTE_STORE(xa, 60)
  LOAD_BUF(xa, 63)
  COMPUTE_STORE(xb, 61)
  COMPUTE_STORE(xc, 62)
  COMPUTE_STORE(xa, 63)

#undef LOAD_BUF
#undef COMPUTE_STORE

  __syncthreads();

  // ---- Phase 2: gate. 8 threads per token, each owns 2 experts. ----
  {
    const int t = tid >> 3;   // token-local 0..63 (= b*8 + s_loc)
    const int j = tid & 7;    // expert-pair index

    float l[16];
#pragma unroll
    for (int i = 0; i < 16; ++i) {
      l[i] = plds[0][t][i] + plds[1][t][i] + plds[2][t][i] + plds[3][t][i] +
             bias_lds[i];
    }

    float m = l[0];
#pragma unroll
    for (int i = 1; i < 16; ++i) m = fmaxf(m, l[i]);

    float ex[16];
    float Z = 0.f;
#pragma unroll
    for (int i = 0; i < 16; ++i) {
      ex[i] = __expf(l[i] - m);
      Z += ex[i];
    }
    const float invZ = 1.0f / Z;

    // top-8 mask via rank count (ties -> lower index, matches lax.top_k)
    const int i0 = 2 * j;
    int c0 = 0, c1 = 0;
#pragma unroll
    for (int k = 0; k < 16; ++k) {
      c0 += (l[k] > l[i0]) || ((l[k] == l[i0]) && (k < i0));
      c1 += (l[k] > l[i0 + 1]) || ((l[k] == l[i0 + 1]) && (k < i0 + 1));
    }
    float2 r;
    r.x = (c0 < 8) ? ex[i0] * invZ : 0.0f;
    r.y = (c1 < 8) ? ex[i0 + 1] * invZ : 0.0f;
    *reinterpret_cast<float2*>(&masked[t][i0]) = r;
  }

  __syncthreads();

  // ---- Phase 3: cross-B normalize + store. ----
  // thread tid = b*64 + s_loc*8 + j  (b = wave id -> coalesced 512B/wave)
  {
    const int b     = tid >> 6;
    const int s_loc = (tid >> 3) & 7;
    const int j     = tid & 7;
    const int i0    = 2 * j;

    float2 den = make_float2(EPS, EPS);
#pragma unroll
    for (int bp = 0; bp < 8; ++bp) {
      const float2 v = *reinterpret_cast<const float2*>(&masked[bp * 8 + s_loc][i0]);
      den.x += v.x;
      den.y += v.y;
    }
    const float2 mv = *reinterpret_cast<const float2*>(&masked[b * 8 + s_loc][i0]);
    float2 r;
    r.x = mv.x * CAPACITY / den.x;
    r.y = mv.y * CAPACITY / den.y;
    *reinterpret_cast<float2*>(
        out + ((size_t)b * Sc + s0 + s_loc) * Ec + i0) = r;
  }
}

// ---------------------------------------------------------------------------
extern "C" void kernel_launch(void* const* d_in, const int* in_sizes, int n_in,
                              void* d_out, int out_size, void* d_ws, size_t ws_size,
                              hipStream_t stream) {
  const float* X    = (const float*)d_in[0];  // [8,4096,2048]
  const float* W    = (const float*)d_in[1];  // [16,2048]
  const float* bias = (const float*)d_in[2];  // [16]
  float* out = (float*)d_out;                 // [8,4096,16] fp32

  k_switchgate<<<NBLK, 512, 0, stream>>>(X, W, bias, out);
}